// Round 23
// baseline (132.513 us; speedup 1.0000x reference)
//
#include <hip/hip_runtime.h>
#include <hip/hip_bf16.h>

#define B_ 2
#define N_ 2048
#define C_ 1024
#define H_ 16
#define D_ 64
#define HALF_ 32

typedef __attribute__((ext_vector_type(8))) __bf16 bf16x8;
typedef __attribute__((ext_vector_type(8))) unsigned short u16x8;
typedef __attribute__((ext_vector_type(4))) float f32x4;
typedef __attribute__((ext_vector_type(16))) float f32x16;

__device__ __forceinline__ unsigned short f2bf(float f) {
  union { float f; unsigned u; } v; v.f = f;
  unsigned r = v.u + 0x7FFFu + ((v.u >> 16) & 1u);
  return (unsigned short)(r >> 16);
}

__device__ __forceinline__ unsigned cvt_pk_bf16(float lo, float hi) {
  unsigned r;
  asm("v_cvt_pk_bf16_f32 %0, %1, %2" : "=v"(r) : "v"(lo), "v"(hi));
  return r;
}

__device__ __forceinline__ void gload_lds16(const void* g, void* l) {
  __builtin_amdgcn_global_load_lds(
      (const __attribute__((address_space(1))) void*)g,
      (__attribute__((address_space(3))) void*)l, 16, 0, 0);
}

// ------- fused cast f32 -> bf16 for x, qkv_w, proj_w + cos/sin float2 table -------
__global__ __launch_bounds__(256) void cast3_f32_bf16(
    const float* __restrict__ a, const float* __restrict__ b,
    const float* __restrict__ c, unsigned short* __restrict__ oa,
    unsigned short* __restrict__ ob, unsigned short* __restrict__ oc,
    const float* __restrict__ cosT, const float* __restrict__ sinT,
    float2* __restrict__ csT) {
  int i = blockIdx.x * 256 + threadIdx.x;
  if (i >= 2097152) {                      // last 256 blocks: cos/sin table
    int i2 = i - 2097152;                  // 0..65535 = N_*HALF_
    csT[i2] = make_float2(cosT[i2], sinT[i2]);
    return;
  }
  const float4* src;
  ushort4* dst;
  int off;
  if (i < 1048576) {                       // x: 4M floats
    src = (const float4*)a; dst = (ushort4*)oa; off = i;
  } else if (i < 1835008) {                // qkv_w: 3M floats
    src = (const float4*)b; dst = (ushort4*)ob; off = i - 1048576;
  } else {                                 // proj_w: 1M floats
    src = (const float4*)c; dst = (ushort4*)oc; off = i - 1835008;
  }
  float4 v = src[off];
  ushort4 o;
  o.x = f2bf(v.x); o.y = f2bf(v.y); o.z = f2bf(v.z); o.w = f2bf(v.w);
  dst[off] = o;
}

// ---------------- GEMM C[M][N] = A[M][K] * Bw[N][K]^T --------------------
// R18 configuration (session best): double-buffered LDS, BK=64, raw s_barrier
// + counted vmcnt(8), T2 XOR-swizzle. Local optimum confirmed by A/B:
// BK=32 quad-ring (R19) and 3-buf/96KB (R21) both regress.
// 1-D grid, XCD-chunked bijective swizzle (gridDim.x % 8 == 0).
template <int EPI>
__global__ __launch_bounds__(256) void gemm_bt(
    const unsigned short* __restrict__ A, const unsigned short* __restrict__ Bw,
    int M, int Nn, int K,
    float* __restrict__ Cout, const float* __restrict__ bias,
    unsigned short* __restrict__ qo, unsigned short* __restrict__ ko,
    unsigned short* __restrict__ vto,
    const float2* __restrict__ csT) {
  __shared__ __align__(16) unsigned short As[2][128][64];
  __shared__ __align__(16) unsigned short Bs[2][128][64];
  const int tid = threadIdx.x;
  const int lane = tid & 63;
  const int wid = tid >> 6;
  const int wm = wid >> 1, wn = wid & 1;
  const int l15 = lane & 15;
  const int g = lane >> 4;

  const int per = gridDim.x >> 3;
  const int f = blockIdx.x;
  const int nat = (f & 7) * per + (f >> 3);
  const int mtiles = M >> 7;
  const int m0 = (nat % mtiles) * 128;
  const int n0 = (nat / mtiles) * 128;

  const int srow = wid * 8 + (lane >> 3);
  // T2 pre-swizzled source chunk: row&7 == (lane>>3)&7 for every j-group
  const int scol = ((lane & 7) ^ ((lane >> 3) & 7)) * 8;
  const int b7r = l15 & 7;   // read-side XOR key (row&7 of fragment rows)

  // stage K-step kt into LDS buffer buf (8 global_load_lds per thread)
  auto stage = [&](int kt, int buf) {
#pragma unroll
    for (int j = 0; j < 4; ++j) {
      gload_lds16(&A[(size_t)(m0 + j * 32 + srow) * K + kt * 64 + scol],
                  &As[buf][j * 32 + wid * 8][0]);
      gload_lds16(&Bw[(size_t)(n0 + j * 32 + srow) * K + kt * 64 + scol],
                  &Bs[buf][j * 32 + wid * 8][0]);
    }
  };

  f32x4 acc[4][4] = {};

  const int nK = K >> 6;
  stage(0, 0);
  stage(1, 1);

  for (int kt = 0; kt < nK; ++kt) {
    const int buf = kt & 1;
    // wait for THIS buffer's loads; leave the next tile's 8 in flight
    if (kt == nK - 1) asm volatile("s_waitcnt vmcnt(0)" ::: "memory");
    else              asm volatile("s_waitcnt vmcnt(8)" ::: "memory");
    __builtin_amdgcn_s_barrier();
    __builtin_amdgcn_sched_barrier(0);
#pragma unroll
    for (int kk = 0; kk < 2; ++kk) {
      bf16x8 af[4], bfv[4];
#pragma unroll
      for (int m = 0; m < 4; ++m)
        af[m] = *reinterpret_cast<const bf16x8*>(
            &As[buf][wm * 64 + m * 16 + l15][((kk * 4 + g) ^ b7r) * 8]);
#pragma unroll
      for (int n = 0; n < 4; ++n)
        bfv[n] = *reinterpret_cast<const bf16x8*>(
            &Bs[buf][wn * 64 + n * 16 + l15][((kk * 4 + g) ^ b7r) * 8]);
#pragma unroll
      for (int m = 0; m < 4; ++m)
#pragma unroll
        for (int n = 0; n < 4; ++n)
          acc[m][n] = __builtin_amdgcn_mfma_f32_16x16x32_bf16(af[m], bfv[n], acc[m][n], 0, 0, 0);
    }
    __builtin_amdgcn_s_barrier();   // all waves done reading buf
    if (kt + 2 < nK) stage(kt + 2, buf);
  }

  if constexpr (EPI == 0) {
#pragma unroll
    for (int n = 0; n < 4; ++n) {
      int col = n0 + wn * 64 + n * 16 + l15;
      float bv = bias[col];
#pragma unroll
      for (int m = 0; m < 4; ++m) {
        int rbase = m0 + wm * 64 + m * 16 + g * 4;
#pragma unroll
        for (int r = 0; r < 4; ++r)
          Cout[(size_t)(rbase + r) * Nn + col] = acc[m][n][r] + bv;
      }
    }
  } else {
    const int which = n0 >> 10;  // block-uniform: 0=q, 1=k, 2=v
    if (which == 2) {
      // v: store TRANSPOSED [bh][d][seq'] with seq' = seq with bits 2<->3
      // swapped (kv->PV-slot involution) so attention's V tile is a LINEAR
      // copy and the P B-fragment needs no cross-lane exchange.
#pragma unroll
      for (int m = 0; m < 4; ++m)
#pragma unroll
        for (int n = 0; n < 4; ++n) {
          int col = n0 + wn * 64 + n * 16 + l15;
          int hc = col & 1023;
          int hh = hc >> 6, d = hc & 63;
          int row0 = m0 + wm * 64 + m * 16 + g * 4;
          int seq0 = row0 & (N_ - 1), bb = row0 >> 11;
          int seqP = (seq0 & ~12) | ((seq0 & 4) << 1) | ((seq0 & 8) >> 1);
          ushort4 pk;
          pk.x = f2bf(acc[m][n][0]); pk.y = f2bf(acc[m][n][1]);
          pk.z = f2bf(acc[m][n][2]); pk.w = f2bf(acc[m][n][3]);
          *reinterpret_cast<ushort4*>(
              &vto[(((size_t)bb * H_ + hh) * D_ + d) * N_ + seqP]) = pk;
        }
    } else {
      unsigned short* dst = (which == 0) ? qo : ko;
      // q gets D^-0.5 AND log2(e) folded in (softmax runs in exp2 domain)
      const float qscale = (which == 0) ? 0.125f * 1.44269504f : 1.0f;
#pragma unroll
      for (int m = 0; m < 4; ++m)
#pragma unroll
        for (int n = 0; n < 4; ++n)
#pragma unroll
          for (int r = 0; r < 4; ++r) {
            int col = n0 + wn * 64 + n * 16 + l15;
            int row = m0 + wm * 64 + m * 16 + g * 4 + r;
            float val = acc[m][n][r];
            float partner = __shfl_xor(val, 1);
            int hc = col & 1023;
            int hh = hc >> 6, d = hc & 63;
            int seq = row & (N_ - 1), bb = row >> 11;
            float2 cs = csT[seq * HALF_ + (d >> 1)];
            float res = (d & 1) ? (partner * cs.y + val * cs.x) : (val * cs.x - partner * cs.y);
            res *= qscale;
            dst[(((size_t)bb * H_ + hh) * N_ + seq) * D_ + d] = f2bf(res);
          }
    }
  }
}

// ---------- flash attention: 8 waves x 32 q-rows, 32x32 MFMA, swapped QK^T ----------
// Max-free softmax (scores provably in [-8,8] log2 units) + att[2] software
// pipeline. exp2 results are written to FRESH p0_/p1_ vectors (never MFMA
// operands) so they live in arch-VGPRs — the MFMA-destined AGPR array is read
// exactly once per element, removing ~100 v_accvgpr moves from the per-tile
// serial softmax path. lrun cross-half combine deferred to the epilogue.
__global__ __launch_bounds__(512, 2) void attn_kernel(
    const unsigned short* __restrict__ q,   // [B*H][N][D] bf16, q pre-scaled
    const unsigned short* __restrict__ k,   // [B*H][N][D]
    const unsigned short* __restrict__ vt,  // [B*H][D][N'] (transposed + slot-permuted)
    unsigned short* __restrict__ o) {       // [B*N][C] bf16
  __shared__ __align__(16) unsigned short Kl[2][64][64];  // [buf][kv][d] swizzled
  __shared__ __align__(16) unsigned short Vl[2][64][64];  // [buf][d][slot] swizzled

  const int tid = threadIdx.x;
  const int lane = tid & 63;
  const int w = tid >> 6;          // 0..7
  const int l31 = lane & 31;
  const int hi = lane >> 5;

  // head-contiguous XCD swizzle: 256 blocks, 32/XCD -> 4 full heads per XCD L2
  const int bid = blockIdx.x;
  const int nat = (bid & 7) * 32 + (bid >> 3);
  const int qt = nat & 7;
  const int bh = nat >> 3;
  const int b = bh >> 4, h = bh & 15;

  const size_t hk = (size_t)bh * N_ * D_;
  const size_t hv = (size_t)bh * D_ * N_;
  const int qrow = qt * 256 + w * 32 + l31;  // this lane's q (B-frag col)

  // Q fragments: B-operand, col=q=l31, k = d = kt*16 + hi*8 + j
  bf16x8 qf[4];
#pragma unroll
  for (int kt = 0; kt < 4; ++kt)
    qf[kt] = *reinterpret_cast<const bf16x8*>(
        &q[hk + (size_t)qrow * D_ + kt * 16 + hi * 8]);

  // staging: 512 threads x (1 K-chunk + 1 V-chunk) of 16B, reg-staged
  const int prow = tid >> 3;                 // 0..63
  const int pchk = tid & 7;
  const int swz = (pchk ^ (prow & 7)) * 8;

  u16x8 kr, vr;
  auto issueK = [&](int t) {
    kr = *reinterpret_cast<const u16x8*>(&k[hk + (size_t)(t * 64 + prow) * D_ + pchk * 8]);
  };
  auto issueV = [&](int t) {
    vr = *reinterpret_cast<const u16x8*>(&vt[hv + (size_t)prow * N_ + t * 64 + pchk * 8]);
  };
  auto commitK = [&](int buf) { *reinterpret_cast<u16x8*>(&Kl[buf][prow][swz]) = kr; };
  auto commitV = [&](int buf) { *reinterpret_cast<u16x8*>(&Vl[buf][prow][swz]) = vr; };

  f32x16 accO[2] = {};
  float lrun = 0.f;   // per-half-wave partial; combined once in epilogue
  const int b7 = l31 & 7;
  const int NT = N_ / 64;

  f32x16 sA[2], sB[2];

  // QK(t) into SC from Kl[t&1]
#define QK_MFMA(T, SC)                                                        \
  do {                                                                        \
    f32x16 z_ = {};                                                           \
    SC[0] = z_; SC[1] = z_;                                                   \
    __builtin_amdgcn_s_setprio(1);                                            \
    _Pragma("unroll")                                                         \
    for (int kb = 0; kb < 2; ++kb)                                            \
      _Pragma("unroll")                                                       \
      for (int kt = 0; kt < 4; ++kt) {                                        \
        bf16x8 kf = *reinterpret_cast<const bf16x8*>(                         \
            &Kl[(T) & 1][kb * 32 + l31][(((kt * 2 + hi) ^ b7)) * 8]);         \
        SC[kb] = __builtin_amdgcn_mfma_f32_32x32x16_bf16(kf, qf[kt], SC[kb], 0, 0, 0); \
      }                                                                       \
    __builtin_amdgcn_s_setprio(0);                                            \
  } while (0)

  // softmax(SP) + PV with Vl[VB]; exp2 lands in fresh VGPR vectors p0_/p1_
#define SMPV(SP, VB)                                                          \
  do {                                                                        \
    f32x16 p0_, p1_;                                                          \
    _Pragma("unroll")                                                         \
    for (int i = 0; i < 16; ++i) {                                            \
      p0_[i] = __builtin_exp2f(SP[0][i]);                                     \
      p1_[i] = __builtin_exp2f(SP[1][i]);                                     \
    }                                                                         \
    float sloc[16];                                                           \
    _Pragma("unroll")                                                         \
    for (int i = 0; i < 16; ++i) sloc[i] = p0_[i] + p1_[i];                   \
    _Pragma("unroll")                                                         \
    for (int st = 8; st > 0; st >>= 1)                                        \
      _Pragma("unroll")                                                       \
      for (int i = 0; i < 8; ++i)                                             \
        if (i < st) sloc[i] += sloc[i + st];                                  \
    lrun += sloc[0];                                                          \
    bf16x8 PA[4];                                                             \
    _Pragma("unroll")                                                         \
    for (int kvc = 0; kvc < 4; ++kvc) {                                       \
      const int base = (kvc & 1) * 8;                                         \
      union { unsigned u[4]; bf16x8 v; } pa;                                  \
      _Pragma("unroll")                                                       \
      for (int wd = 0; wd < 4; ++wd)                                          \
        pa.u[wd] = (kvc >> 1)                                                 \
            ? cvt_pk_bf16(p1_[base + 2 * wd], p1_[base + 2 * wd + 1])         \
            : cvt_pk_bf16(p0_[base + 2 * wd], p0_[base + 2 * wd + 1]);        \
      PA[kvc] = pa.v;                                                         \
    }                                                                         \
    __builtin_amdgcn_s_setprio(1);                                            \
    _Pragma("unroll")                                                         \
    for (int db = 0; db < 2; ++db)                                            \
      _Pragma("unroll")                                                       \
      for (int kvc = 0; kvc < 4; ++kvc) {                                     \
        bf16x8 vf = *reinterpret_cast<const bf16x8*>(                         \
            &Vl[VB][db * 32 + l31][(((kvc * 2 + hi) ^ b7)) * 8]);             \
        accO[db] = __builtin_amdgcn_mfma_f32_32x32x16_bf16(vf, PA[kvc], accO[db], 0, 0, 0); \
      }                                                                       \
    __builtin_amdgcn_s_setprio(0);                                            \
  } while (0)

  // iter t: QK(t) || softmax+PV(t-1); stage K(t+1) into (t+1)&1, V(t) into t&1.
#define BODY(T, SP, SC)                                                       \
  do {                                                                        \
    const int t_ = (T);                                                       \
    if (t_ + 1 < NT) issueK(t_ + 1);                                          \
    issueV(t_);                                                               \
    QK_MFMA(t_, SC);                                                          \
    SMPV(SP, (t_ - 1) & 1);                                                   \
    if (t_ + 1 < NT) commitK((t_ + 1) & 1);                                   \
    commitV(t_ & 1);                                                          \
    __syncthreads();                                                          \
  } while (0)

  // prologue: stage K(0)
  issueK(0);
  commitK(0);
  __syncthreads();

  // iter 0 (peeled: no previous tile)
  issueK(1);
  issueV(0);
  QK_MFMA(0, sA);
  commitK(1);
  commitV(0);
  __syncthreads();

  for (int tt = 1; tt + 1 < NT; tt += 2) {
    BODY(tt, sA, sB);
    BODY(tt + 1, sB, sA);
  }
  BODY(NT - 1, sA, sB);  // NT even: last iter, prev state in sA

  // tail: finish tile NT-1 (state in sB), V buffer (NT-1)&1
  SMPV(sB, (NT - 1) & 1);

  // epilogue: combine the two half-wave lrun partials once, then normalize
  {
    unsigned ua = __float_as_uint(lrun), ub = ua;
    auto rr = __builtin_amdgcn_permlane32_swap(ua, ub, false, false);
    lrun = __uint_as_float(rr[0]) + __uint_as_float(rr[1]);
  }
  float rl = 1.0f / lrun;
  const size_t obase = ((size_t)b * N_ + qrow) * C_ + h * 64;
#pragma unroll
  for (int db = 0; db < 2; ++db)
#pragma unroll
    for (int rg = 0; rg < 4; ++rg) {
      ushort4 pk;
      pk.x = f2bf(accO[db][rg * 4 + 0] * rl);
      pk.y = f2bf(accO[db][rg * 4 + 1] * rl);
      pk.z = f2bf(accO[db][rg * 4 + 2] * rl);
      pk.w = f2bf(accO[db][rg * 4 + 3] * rl);
      *reinterpret_cast<ushort4*>(&o[obase + db * 32 + rg * 8 + hi * 4]) = pk;
    }
#undef BODY
#undef SMPV
#undef QK_MFMA
}

extern "C" void kernel_launch(void* const* d_in, const int* in_sizes, int n_in,
                              void* d_out, int out_size, void* d_ws, size_t ws_size,
                              hipStream_t stream) {
  const float* x      = (const float*)d_in[0];
  const float* qkv_w  = (const float*)d_in[1];
  const float* proj_w = (const float*)d_in[2];
  const float* proj_b = (const float*)d_in[3];
  const float* cosT   = (const float*)d_in[4];
  const float* sinT   = (const float*)d_in[5];
  float* out = (float*)d_out;

  unsigned short* xb     = (unsigned short*)d_ws;                 // 4096*1024
  unsigned short* wqkvb  = xb + (size_t)4096 * 1024;              // 3072*1024
  unsigned short* wprojb = wqkvb + (size_t)3072 * 1024;           // 1024*1024
  unsigned short* qb     = wprojb + (size_t)1024 * 1024;          // 32*2048*64
  unsigned short* kb     = qb + (size_t)32 * 2048 * 64;
  unsigned short* vtb    = kb + (size_t)32 * 2048 * 64;           // [bh][d][n']
  unsigned short* ab     = vtb + (size_t)32 * 2048 * 64;          // 4096*1024
  float2* csT            = (float2*)(ab + (size_t)4096 * 1024);   // 2048*32 float2

  cast3_f32_bf16<<<8448, 256, 0, stream>>>(x, qkv_w, proj_w, xb, wqkvb, wprojb,
                                           cosT, sinT, csT);

  gemm_bt<1><<<768, 256, 0, stream>>>(xb, wqkvb, 4096, 3072, 1024,
                                      nullptr, nullptr, qb, kb, vtb, csT);

  attn_kernel<<<256, 512, 0, stream>>>(qb, kb, vtb, ab);

  gemm_bt<0><<<256, 256, 0, stream>>>(ab, wprojb, 4096, 1024, 1024,
                                      out, proj_b, nullptr, nullptr, nullptr,
                                      csT);
}

// Round 24
// 131.874 us; speedup vs baseline: 1.0048x; 1.0048x over previous
//
#include <hip/hip_runtime.h>
#include <hip/hip_bf16.h>

#define B_ 2
#define N_ 2048
#define C_ 1024
#define H_ 16
#define D_ 64
#define HALF_ 32

typedef __attribute__((ext_vector_type(8))) __bf16 bf16x8;
typedef __attribute__((ext_vector_type(8))) unsigned short u16x8;
typedef __attribute__((ext_vector_type(4))) float f32x4;
typedef __attribute__((ext_vector_type(16))) float f32x16;

__device__ __forceinline__ unsigned short f2bf(float f) {
  union { float f; unsigned u; } v; v.f = f;
  unsigned r = v.u + 0x7FFFu + ((v.u >> 16) & 1u);
  return (unsigned short)(r >> 16);
}

__device__ __forceinline__ unsigned cvt_pk_bf16(float lo, float hi) {
  unsigned r;
  asm("v_cvt_pk_bf16_f32 %0, %1, %2" : "=v"(r) : "v"(lo), "v"(hi));
  return r;
}

__device__ __forceinline__ void gload_lds16(const void* g, void* l) {
  __builtin_amdgcn_global_load_lds(
      (const __attribute__((address_space(1))) void*)g,
      (__attribute__((address_space(3))) void*)l, 16, 0, 0);
}

// ------- fused cast f32 -> bf16 for x, qkv_w, proj_w + cos/sin float2 table -------
__global__ __launch_bounds__(256) void cast3_f32_bf16(
    const float* __restrict__ a, const float* __restrict__ b,
    const float* __restrict__ c, unsigned short* __restrict__ oa,
    unsigned short* __restrict__ ob, unsigned short* __restrict__ oc,
    const float* __restrict__ cosT, const float* __restrict__ sinT,
    float2* __restrict__ csT) {
  int i = blockIdx.x * 256 + threadIdx.x;
  if (i >= 2097152) {                      // last 256 blocks: cos/sin table
    int i2 = i - 2097152;                  // 0..65535 = N_*HALF_
    csT[i2] = make_float2(cosT[i2], sinT[i2]);
    return;
  }
  const float4* src;
  ushort4* dst;
  int off;
  if (i < 1048576) {                       // x: 4M floats
    src = (const float4*)a; dst = (ushort4*)oa; off = i;
  } else if (i < 1835008) {                // qkv_w: 3M floats
    src = (const float4*)b; dst = (ushort4*)ob; off = i - 1048576;
  } else {                                 // proj_w: 1M floats
    src = (const float4*)c; dst = (ushort4*)oc; off = i - 1835008;
  }
  float4 v = src[off];
  ushort4 o;
  o.x = f2bf(v.x); o.y = f2bf(v.y); o.z = f2bf(v.z); o.w = f2bf(v.w);
  dst[off] = o;
}

// ---------------- GEMM C[M][N] = A[M][K] * Bw[N][K]^T --------------------
// R18 configuration (session best): double-buffered LDS, BK=64, raw s_barrier
// + counted vmcnt(8), T2 XOR-swizzle. Local optimum confirmed by A/B:
// BK=32 quad-ring (R19) and 3-buf/96KB (R21) both regress.
// 1-D grid, XCD-chunked bijective swizzle (gridDim.x % 8 == 0).
template <int EPI>
__global__ __launch_bounds__(256) void gemm_bt(
    const unsigned short* __restrict__ A, const unsigned short* __restrict__ Bw,
    int M, int Nn, int K,
    float* __restrict__ Cout, const float* __restrict__ bias,
    unsigned short* __restrict__ qo, unsigned short* __restrict__ ko,
    unsigned short* __restrict__ vto,
    const float2* __restrict__ csT) {
  __shared__ __align__(16) unsigned short As[2][128][64];
  __shared__ __align__(16) unsigned short Bs[2][128][64];
  const int tid = threadIdx.x;
  const int lane = tid & 63;
  const int wid = tid >> 6;
  const int wm = wid >> 1, wn = wid & 1;
  const int l15 = lane & 15;
  const int g = lane >> 4;

  const int per = gridDim.x >> 3;
  const int f = blockIdx.x;
  const int nat = (f & 7) * per + (f >> 3);
  const int mtiles = M >> 7;
  const int m0 = (nat % mtiles) * 128;
  const int n0 = (nat / mtiles) * 128;

  const int srow = wid * 8 + (lane >> 3);
  // T2 pre-swizzled source chunk: row&7 == (lane>>3)&7 for every j-group
  const int scol = ((lane & 7) ^ ((lane >> 3) & 7)) * 8;
  const int b7r = l15 & 7;   // read-side XOR key (row&7 of fragment rows)

  // stage K-step kt into LDS buffer buf (8 global_load_lds per thread)
  auto stage = [&](int kt, int buf) {
#pragma unroll
    for (int j = 0; j < 4; ++j) {
      gload_lds16(&A[(size_t)(m0 + j * 32 + srow) * K + kt * 64 + scol],
                  &As[buf][j * 32 + wid * 8][0]);
      gload_lds16(&Bw[(size_t)(n0 + j * 32 + srow) * K + kt * 64 + scol],
                  &Bs[buf][j * 32 + wid * 8][0]);
    }
  };

  f32x4 acc[4][4] = {};

  const int nK = K >> 6;
  stage(0, 0);
  stage(1, 1);

  for (int kt = 0; kt < nK; ++kt) {
    const int buf = kt & 1;
    // wait for THIS buffer's loads; leave the next tile's 8 in flight
    if (kt == nK - 1) asm volatile("s_waitcnt vmcnt(0)" ::: "memory");
    else              asm volatile("s_waitcnt vmcnt(8)" ::: "memory");
    __builtin_amdgcn_s_barrier();
    __builtin_amdgcn_sched_barrier(0);
#pragma unroll
    for (int kk = 0; kk < 2; ++kk) {
      bf16x8 af[4], bfv[4];
#pragma unroll
      for (int m = 0; m < 4; ++m)
        af[m] = *reinterpret_cast<const bf16x8*>(
            &As[buf][wm * 64 + m * 16 + l15][((kk * 4 + g) ^ b7r) * 8]);
#pragma unroll
      for (int n = 0; n < 4; ++n)
        bfv[n] = *reinterpret_cast<const bf16x8*>(
            &Bs[buf][wn * 64 + n * 16 + l15][((kk * 4 + g) ^ b7r) * 8]);
#pragma unroll
      for (int m = 0; m < 4; ++m)
#pragma unroll
        for (int n = 0; n < 4; ++n)
          acc[m][n] = __builtin_amdgcn_mfma_f32_16x16x32_bf16(af[m], bfv[n], acc[m][n], 0, 0, 0);
    }
    __builtin_amdgcn_s_barrier();   // all waves done reading buf
    if (kt + 2 < nK) stage(kt + 2, buf);
  }

  if constexpr (EPI == 0) {
#pragma unroll
    for (int n = 0; n < 4; ++n) {
      int col = n0 + wn * 64 + n * 16 + l15;
      float bv = bias[col];
#pragma unroll
      for (int m = 0; m < 4; ++m) {
        int rbase = m0 + wm * 64 + m * 16 + g * 4;
#pragma unroll
        for (int r = 0; r < 4; ++r)
          Cout[(size_t)(rbase + r) * Nn + col] = acc[m][n][r] + bv;
      }
    }
  } else {
    const int which = n0 >> 10;  // block-uniform: 0=q, 1=k, 2=v
    if (which == 2) {
      // v: store TRANSPOSED [bh][d][seq'] with seq' = seq with bits 2<->3
      // swapped (kv->PV-slot involution) so attention's V tile is a LINEAR
      // copy and the P B-fragment needs no cross-lane exchange.
#pragma unroll
      for (int m = 0; m < 4; ++m)
#pragma unroll
        for (int n = 0; n < 4; ++n) {
          int col = n0 + wn * 64 + n * 16 + l15;
          int hc = col & 1023;
          int hh = hc >> 6, d = hc & 63;
          int row0 = m0 + wm * 64 + m * 16 + g * 4;
          int seq0 = row0 & (N_ - 1), bb = row0 >> 11;
          int seqP = (seq0 & ~12) | ((seq0 & 4) << 1) | ((seq0 & 8) >> 1);
          ushort4 pk;
          pk.x = f2bf(acc[m][n][0]); pk.y = f2bf(acc[m][n][1]);
          pk.z = f2bf(acc[m][n][2]); pk.w = f2bf(acc[m][n][3]);
          *reinterpret_cast<ushort4*>(
              &vto[(((size_t)bb * H_ + hh) * D_ + d) * N_ + seqP]) = pk;
        }
    } else {
      unsigned short* dst = (which == 0) ? qo : ko;
      // q gets D^-0.5 AND log2(e) folded in (softmax runs in exp2 domain)
      const float qscale = (which == 0) ? 0.125f * 1.44269504f : 1.0f;
#pragma unroll
      for (int m = 0; m < 4; ++m)
#pragma unroll
        for (int n = 0; n < 4; ++n)
#pragma unroll
          for (int r = 0; r < 4; ++r) {
            int col = n0 + wn * 64 + n * 16 + l15;
            int row = m0 + wm * 64 + m * 16 + g * 4 + r;
            float val = acc[m][n][r];
            float partner = __shfl_xor(val, 1);
            int hc = col & 1023;
            int hh = hc >> 6, d = hc & 63;
            int seq = row & (N_ - 1), bb = row >> 11;
            float2 cs = csT[seq * HALF_ + (d >> 1)];
            float res = (d & 1) ? (partner * cs.y + val * cs.x) : (val * cs.x - partner * cs.y);
            res *= qscale;
            dst[(((size_t)bb * H_ + hh) * N_ + seq) * D_ + d] = f2bf(res);
          }
    }
  }
}

// ---------- flash attention: 8 waves x 32 q-rows, 32x32 MFMA, swapped QK^T ----------
// Max-free softmax (scores provably in [-8,8] log2 units) + att[2] software
// pipeline. MFMA chains INTERLEAVED: kt-outer/kb-inner (QK) and kvc-outer/
// db-inner (PV) alternate the two independent accumulate chains, doubling
// dependency distance on the matrix pipe. lrun combine deferred to epilogue.
__global__ __launch_bounds__(512, 2) void attn_kernel(
    const unsigned short* __restrict__ q,   // [B*H][N][D] bf16, q pre-scaled
    const unsigned short* __restrict__ k,   // [B*H][N][D]
    const unsigned short* __restrict__ vt,  // [B*H][D][N'] (transposed + slot-permuted)
    unsigned short* __restrict__ o) {       // [B*N][C] bf16
  __shared__ __align__(16) unsigned short Kl[2][64][64];  // [buf][kv][d] swizzled
  __shared__ __align__(16) unsigned short Vl[2][64][64];  // [buf][d][slot] swizzled

  const int tid = threadIdx.x;
  const int lane = tid & 63;
  const int w = tid >> 6;          // 0..7
  const int l31 = lane & 31;
  const int hi = lane >> 5;

  // head-contiguous XCD swizzle: 256 blocks, 32/XCD -> 4 full heads per XCD L2
  const int bid = blockIdx.x;
  const int nat = (bid & 7) * 32 + (bid >> 3);
  const int qt = nat & 7;
  const int bh = nat >> 3;
  const int b = bh >> 4, h = bh & 15;

  const size_t hk = (size_t)bh * N_ * D_;
  const size_t hv = (size_t)bh * D_ * N_;
  const int qrow = qt * 256 + w * 32 + l31;  // this lane's q (B-frag col)

  // Q fragments: B-operand, col=q=l31, k = d = kt*16 + hi*8 + j
  bf16x8 qf[4];
#pragma unroll
  for (int kt = 0; kt < 4; ++kt)
    qf[kt] = *reinterpret_cast<const bf16x8*>(
        &q[hk + (size_t)qrow * D_ + kt * 16 + hi * 8]);

  // staging: 512 threads x (1 K-chunk + 1 V-chunk) of 16B, reg-staged
  const int prow = tid >> 3;                 // 0..63
  const int pchk = tid & 7;
  const int swz = (pchk ^ (prow & 7)) * 8;

  u16x8 kr, vr;
  auto issueK = [&](int t) {
    kr = *reinterpret_cast<const u16x8*>(&k[hk + (size_t)(t * 64 + prow) * D_ + pchk * 8]);
  };
  auto issueV = [&](int t) {
    vr = *reinterpret_cast<const u16x8*>(&vt[hv + (size_t)prow * N_ + t * 64 + pchk * 8]);
  };
  auto commitK = [&](int buf) { *reinterpret_cast<u16x8*>(&Kl[buf][prow][swz]) = kr; };
  auto commitV = [&](int buf) { *reinterpret_cast<u16x8*>(&Vl[buf][prow][swz]) = vr; };

  f32x16 accO[2] = {};
  float lrun = 0.f;   // per-half-wave partial; combined once in epilogue
  const int b7 = l31 & 7;
  const int NT = N_ / 64;

  f32x16 sA[2], sB[2];

  // QK(t) into SC from Kl[t&1] — kt OUTER / kb INNER: the two accumulate
  // chains (SC[0], SC[1]) alternate on the matrix pipe.
#define QK_MFMA(T, SC)                                                        \
  do {                                                                        \
    f32x16 z_ = {};                                                           \
    SC[0] = z_; SC[1] = z_;                                                   \
    __builtin_amdgcn_s_setprio(1);                                            \
    _Pragma("unroll")                                                         \
    for (int kt = 0; kt < 4; ++kt)                                            \
      _Pragma("unroll")                                                       \
      for (int kb = 0; kb < 2; ++kb) {                                        \
        bf16x8 kf = *reinterpret_cast<const bf16x8*>(                         \
            &Kl[(T) & 1][kb * 32 + l31][(((kt * 2 + hi) ^ b7)) * 8]);         \
        SC[kb] = __builtin_amdgcn_mfma_f32_32x32x16_bf16(kf, qf[kt], SC[kb], 0, 0, 0); \
      }                                                                       \
    __builtin_amdgcn_s_setprio(0);                                            \
  } while (0)

  // softmax(SP) + PV with Vl[VB] — kvc OUTER / db INNER interleaves accO[0/1]
#define SMPV(SP, VB)                                                          \
  do {                                                                        \
    _Pragma("unroll")                                                         \
    for (int kb = 0; kb < 2; ++kb)                                            \
      _Pragma("unroll")                                                       \
      for (int i = 0; i < 16; ++i) SP[kb][i] = __builtin_exp2f(SP[kb][i]);    \
    float sloc[16];                                                           \
    _Pragma("unroll")                                                         \
    for (int i = 0; i < 16; ++i) sloc[i] = SP[0][i] + SP[1][i];               \
    _Pragma("unroll")                                                         \
    for (int st = 8; st > 0; st >>= 1)                                        \
      _Pragma("unroll")                                                       \
      for (int i = 0; i < 8; ++i)                                             \
        if (i < st) sloc[i] += sloc[i + st];                                  \
    lrun += sloc[0];                                                          \
    bf16x8 PA[4];                                                             \
    _Pragma("unroll")                                                         \
    for (int kvc = 0; kvc < 4; ++kvc) {                                       \
      const int kb = kvc >> 1, base = (kvc & 1) * 8;                          \
      union { unsigned u[4]; bf16x8 v; } pa;                                  \
      _Pragma("unroll")                                                       \
      for (int wd = 0; wd < 4; ++wd)                                          \
        pa.u[wd] = cvt_pk_bf16(SP[kb][base + 2 * wd], SP[kb][base + 2 * wd + 1]); \
      PA[kvc] = pa.v;                                                         \
    }                                                                         \
    __builtin_amdgcn_s_setprio(1);                                            \
    _Pragma("unroll")                                                         \
    for (int kvc = 0; kvc < 4; ++kvc)                                         \
      _Pragma("unroll")                                                       \
      for (int db = 0; db < 2; ++db) {                                        \
        bf16x8 vf = *reinterpret_cast<const bf16x8*>(                         \
            &Vl[VB][db * 32 + l31][(((kvc * 2 + hi) ^ b7)) * 8]);             \
        accO[db] = __builtin_amdgcn_mfma_f32_32x32x16_bf16(vf, PA[kvc], accO[db], 0, 0, 0); \
      }                                                                       \
    __builtin_amdgcn_s_setprio(0);                                            \
  } while (0)

  // iter t: QK(t) || softmax+PV(t-1); stage K(t+1) into (t+1)&1, V(t) into t&1.
#define BODY(T, SP, SC)                                                       \
  do {                                                                        \
    const int t_ = (T);                                                       \
    if (t_ + 1 < NT) issueK(t_ + 1);                                          \
    issueV(t_);                                                               \
    QK_MFMA(t_, SC);                                                          \
    SMPV(SP, (t_ - 1) & 1);                                                   \
    if (t_ + 1 < NT) commitK((t_ + 1) & 1);                                   \
    commitV(t_ & 1);                                                          \
    __syncthreads();                                                          \
  } while (0)

  // prologue: stage K(0)
  issueK(0);
  commitK(0);
  __syncthreads();

  // iter 0 (peeled: no previous tile)
  issueK(1);
  issueV(0);
  QK_MFMA(0, sA);
  commitK(1);
  commitV(0);
  __syncthreads();

  for (int tt = 1; tt + 1 < NT; tt += 2) {
    BODY(tt, sA, sB);
    BODY(tt + 1, sB, sA);
  }
  BODY(NT - 1, sA, sB);  // NT even: last iter, prev state in sA

  // tail: finish tile NT-1 (state in sB), V buffer (NT-1)&1
  SMPV(sB, (NT - 1) & 1);

  // epilogue: combine the two half-wave lrun partials once, then normalize
  {
    unsigned ua = __float_as_uint(lrun), ub = ua;
    auto rr = __builtin_amdgcn_permlane32_swap(ua, ub, false, false);
    lrun = __uint_as_float(rr[0]) + __uint_as_float(rr[1]);
  }
  float rl = 1.0f / lrun;
  const size_t obase = ((size_t)b * N_ + qrow) * C_ + h * 64;
#pragma unroll
  for (int db = 0; db < 2; ++db)
#pragma unroll
    for (int rg = 0; rg < 4; ++rg) {
      ushort4 pk;
      pk.x = f2bf(accO[db][rg * 4 + 0] * rl);
      pk.y = f2bf(accO[db][rg * 4 + 1] * rl);
      pk.z = f2bf(accO[db][rg * 4 + 2] * rl);
      pk.w = f2bf(accO[db][rg * 4 + 3] * rl);
      *reinterpret_cast<ushort4*>(&o[obase + db * 32 + rg * 8 + hi * 4]) = pk;
    }
#undef BODY
#undef SMPV
#undef QK_MFMA
}

extern "C" void kernel_launch(void* const* d_in, const int* in_sizes, int n_in,
                              void* d_out, int out_size, void* d_ws, size_t ws_size,
                              hipStream_t stream) {
  const float* x      = (const float*)d_in[0];
  const float* qkv_w  = (const float*)d_in[1];
  const float* proj_w = (const float*)d_in[2];
  const float* proj_b = (const float*)d_in[3];
  const float* cosT   = (const float*)d_in[4];
  const float* sinT   = (const float*)d_in[5];
  float* out = (float*)d_out;

  unsigned short* xb     = (unsigned short*)d_ws;                 // 4096*1024
  unsigned short* wqkvb  = xb + (size_t)4096 * 1024;              // 3072*1024
  unsigned short* wprojb = wqkvb + (size_t)3072 * 1024;           // 1024*1024
  unsigned short* qb     = wprojb + (size_t)1024 * 1024;          // 32*2048*64
  unsigned short* kb     = qb + (size_t)32 * 2048 * 64;
  unsigned short* vtb    = kb + (size_t)32 * 2048 * 64;           // [bh][d][n']
  unsigned short* ab     = vtb + (size_t)32 * 2048 * 64;          // 4096*1024
  float2* csT            = (float2*)(ab + (size_t)4096 * 1024);   // 2048*32 float2

  cast3_f32_bf16<<<8448, 256, 0, stream>>>(x, qkv_w, proj_w, xb, wqkvb, wprojb,
                                           cosT, sinT, csT);

  gemm_bt<1><<<768, 256, 0, stream>>>(xb, wqkvb, 4096, 3072, 1024,
                                      nullptr, nullptr, qb, kb, vtb, csT);

  attn_kernel<<<256, 512, 0, stream>>>(qb, kb, vtb, ab);

  gemm_bt<0><<<256, 256, 0, stream>>>(ab, wprojb, 4096, 1024, 1024,
                                      out, proj_b, nullptr, nullptr, nullptr,
                                      csT);
}

// Round 25
// 131.272 us; speedup vs baseline: 1.0095x; 1.0046x over previous
//
#include <hip/hip_runtime.h>
#include <hip/hip_bf16.h>

#define B_ 2
#define N_ 2048
#define C_ 1024
#define H_ 16
#define D_ 64
#define HALF_ 32

typedef __attribute__((ext_vector_type(8))) __bf16 bf16x8;
typedef __attribute__((ext_vector_type(8))) unsigned short u16x8;
typedef __attribute__((ext_vector_type(4))) float f32x4;
typedef __attribute__((ext_vector_type(16))) float f32x16;

__device__ __forceinline__ unsigned short f2bf(float f) {
  union { float f; unsigned u; } v; v.f = f;
  unsigned r = v.u + 0x7FFFu + ((v.u >> 16) & 1u);
  return (unsigned short)(r >> 16);
}

__device__ __forceinline__ unsigned cvt_pk_bf16(float lo, float hi) {
  unsigned r;
  asm("v_cvt_pk_bf16_f32 %0, %1, %2" : "=v"(r) : "v"(lo), "v"(hi));
  return r;
}

__device__ __forceinline__ void gload_lds16(const void* g, void* l) {
  __builtin_amdgcn_global_load_lds(
      (const __attribute__((address_space(1))) void*)g,
      (__attribute__((address_space(3))) void*)l, 16, 0, 0);
}

// ------- fused cast f32 -> bf16 for x, qkv_w, proj_w + cos/sin float2 table -------
__global__ __launch_bounds__(256) void cast3_f32_bf16(
    const float* __restrict__ a, const float* __restrict__ b,
    const float* __restrict__ c, unsigned short* __restrict__ oa,
    unsigned short* __restrict__ ob, unsigned short* __restrict__ oc,
    const float* __restrict__ cosT, const float* __restrict__ sinT,
    float2* __restrict__ csT) {
  int i = blockIdx.x * 256 + threadIdx.x;
  if (i >= 2097152) {                      // last 256 blocks: cos/sin table
    int i2 = i - 2097152;                  // 0..65535 = N_*HALF_
    csT[i2] = make_float2(cosT[i2], sinT[i2]);
    return;
  }
  const float4* src;
  ushort4* dst;
  int off;
  if (i < 1048576) {                       // x: 4M floats
    src = (const float4*)a; dst = (ushort4*)oa; off = i;
  } else if (i < 1835008) {                // qkv_w: 3M floats
    src = (const float4*)b; dst = (ushort4*)ob; off = i - 1048576;
  } else {                                 // proj_w: 1M floats
    src = (const float4*)c; dst = (ushort4*)oc; off = i - 1835008;
  }
  float4 v = src[off];
  ushort4 o;
  o.x = f2bf(v.x); o.y = f2bf(v.y); o.z = f2bf(v.z); o.w = f2bf(v.w);
  dst[off] = o;
}

// ---------------- GEMM C[M][N] = A[M][K] * Bw[N][K]^T --------------------
// R18 configuration (session best): double-buffered LDS, BK=64, raw s_barrier
// + counted vmcnt(8), T2 XOR-swizzle. Local optimum confirmed by A/B:
// BK=32 quad-ring (R19) and 3-buf/96KB (R21) both regress.
// 1-D grid, XCD-chunked bijective swizzle (gridDim.x % 8 == 0).
template <int EPI>
__global__ __launch_bounds__(256) void gemm_bt(
    const unsigned short* __restrict__ A, const unsigned short* __restrict__ Bw,
    int M, int Nn, int K,
    float* __restrict__ Cout, const float* __restrict__ bias,
    unsigned short* __restrict__ qo, unsigned short* __restrict__ ko,
    unsigned short* __restrict__ vto,
    const float2* __restrict__ csT) {
  __shared__ __align__(16) unsigned short As[2][128][64];
  __shared__ __align__(16) unsigned short Bs[2][128][64];
  const int tid = threadIdx.x;
  const int lane = tid & 63;
  const int wid = tid >> 6;
  const int wm = wid >> 1, wn = wid & 1;
  const int l15 = lane & 15;
  const int g = lane >> 4;

  const int per = gridDim.x >> 3;
  const int f = blockIdx.x;
  const int nat = (f & 7) * per + (f >> 3);
  const int mtiles = M >> 7;
  const int m0 = (nat % mtiles) * 128;
  const int n0 = (nat / mtiles) * 128;

  const int srow = wid * 8 + (lane >> 3);
  // T2 pre-swizzled source chunk: row&7 == (lane>>3)&7 for every j-group
  const int scol = ((lane & 7) ^ ((lane >> 3) & 7)) * 8;
  const int b7r = l15 & 7;   // read-side XOR key (row&7 of fragment rows)

  // stage K-step kt into LDS buffer buf (8 global_load_lds per thread)
  auto stage = [&](int kt, int buf) {
#pragma unroll
    for (int j = 0; j < 4; ++j) {
      gload_lds16(&A[(size_t)(m0 + j * 32 + srow) * K + kt * 64 + scol],
                  &As[buf][j * 32 + wid * 8][0]);
      gload_lds16(&Bw[(size_t)(n0 + j * 32 + srow) * K + kt * 64 + scol],
                  &Bs[buf][j * 32 + wid * 8][0]);
    }
  };

  f32x4 acc[4][4] = {};

  const int nK = K >> 6;
  stage(0, 0);
  stage(1, 1);

  for (int kt = 0; kt < nK; ++kt) {
    const int buf = kt & 1;
    // wait for THIS buffer's loads; leave the next tile's 8 in flight
    if (kt == nK - 1) asm volatile("s_waitcnt vmcnt(0)" ::: "memory");
    else              asm volatile("s_waitcnt vmcnt(8)" ::: "memory");
    __builtin_amdgcn_s_barrier();
    __builtin_amdgcn_sched_barrier(0);
#pragma unroll
    for (int kk = 0; kk < 2; ++kk) {
      bf16x8 af[4], bfv[4];
#pragma unroll
      for (int m = 0; m < 4; ++m)
        af[m] = *reinterpret_cast<const bf16x8*>(
            &As[buf][wm * 64 + m * 16 + l15][((kk * 4 + g) ^ b7r) * 8]);
#pragma unroll
      for (int n = 0; n < 4; ++n)
        bfv[n] = *reinterpret_cast<const bf16x8*>(
            &Bs[buf][wn * 64 + n * 16 + l15][((kk * 4 + g) ^ b7r) * 8]);
#pragma unroll
      for (int m = 0; m < 4; ++m)
#pragma unroll
        for (int n = 0; n < 4; ++n)
          acc[m][n] = __builtin_amdgcn_mfma_f32_16x16x32_bf16(af[m], bfv[n], acc[m][n], 0, 0, 0);
    }
    __builtin_amdgcn_s_barrier();   // all waves done reading buf
    if (kt + 2 < nK) stage(kt + 2, buf);
  }

  if constexpr (EPI == 0) {
#pragma unroll
    for (int n = 0; n < 4; ++n) {
      int col = n0 + wn * 64 + n * 16 + l15;
      float bv = bias[col];
#pragma unroll
      for (int m = 0; m < 4; ++m) {
        int rbase = m0 + wm * 64 + m * 16 + g * 4;
#pragma unroll
        for (int r = 0; r < 4; ++r)
          Cout[(size_t)(rbase + r) * Nn + col] = acc[m][n][r] + bv;
      }
    }
  } else {
    const int which = n0 >> 10;  // block-uniform: 0=q, 1=k, 2=v
    if (which == 2) {
      // v: store TRANSPOSED [bh][d][seq'] with seq' = seq with bits 2<->3
      // swapped (kv->PV-slot involution) so attention's V tile is a LINEAR
      // copy and the P B-fragment needs no cross-lane exchange.
#pragma unroll
      for (int m = 0; m < 4; ++m)
#pragma unroll
        for (int n = 0; n < 4; ++n) {
          int col = n0 + wn * 64 + n * 16 + l15;
          int hc = col & 1023;
          int hh = hc >> 6, d = hc & 63;
          int row0 = m0 + wm * 64 + m * 16 + g * 4;
          int seq0 = row0 & (N_ - 1), bb = row0 >> 11;
          int seqP = (seq0 & ~12) | ((seq0 & 4) << 1) | ((seq0 & 8) >> 1);
          ushort4 pk;
          pk.x = f2bf(acc[m][n][0]); pk.y = f2bf(acc[m][n][1]);
          pk.z = f2bf(acc[m][n][2]); pk.w = f2bf(acc[m][n][3]);
          *reinterpret_cast<ushort4*>(
              &vto[(((size_t)bb * H_ + hh) * D_ + d) * N_ + seqP]) = pk;
        }
    } else {
      unsigned short* dst = (which == 0) ? qo : ko;
      // q gets D^-0.5 AND log2(e) folded in (softmax runs in exp2 domain)
      const float qscale = (which == 0) ? 0.125f * 1.44269504f : 1.0f;
#pragma unroll
      for (int m = 0; m < 4; ++m)
#pragma unroll
        for (int n = 0; n < 4; ++n)
#pragma unroll
          for (int r = 0; r < 4; ++r) {
            int col = n0 + wn * 64 + n * 16 + l15;
            int row = m0 + wm * 64 + m * 16 + g * 4 + r;
            float val = acc[m][n][r];
            float partner = __shfl_xor(val, 1);
            int hc = col & 1023;
            int hh = hc >> 6, d = hc & 63;
            int seq = row & (N_ - 1), bb = row >> 11;
            float2 cs = csT[seq * HALF_ + (d >> 1)];
            float res = (d & 1) ? (partner * cs.y + val * cs.x) : (val * cs.x - partner * cs.y);
            res *= qscale;
            dst[(((size_t)bb * H_ + hh) * N_ + seq) * D_ + d] = f2bf(res);
          }
    }
  }
}

// ---------- flash attention: 8 waves x 32 q-rows, 32x32 MFMA, swapped QK^T ----------
// Max-free softmax (scores provably in [-8,8] log2 units) + att[2] software
// pipeline. NO s_setprio: this kernel is 8-wave LOCKSTEP (single barrier per
// tile), the regime where T5 measured NEGATIVE (m190); it was never A/B'd
// here. MFMA chains interleaved; lrun combine deferred to epilogue.
__global__ __launch_bounds__(512, 2) void attn_kernel(
    const unsigned short* __restrict__ q,   // [B*H][N][D] bf16, q pre-scaled
    const unsigned short* __restrict__ k,   // [B*H][N][D]
    const unsigned short* __restrict__ vt,  // [B*H][D][N'] (transposed + slot-permuted)
    unsigned short* __restrict__ o) {       // [B*N][C] bf16
  __shared__ __align__(16) unsigned short Kl[2][64][64];  // [buf][kv][d] swizzled
  __shared__ __align__(16) unsigned short Vl[2][64][64];  // [buf][d][slot] swizzled

  const int tid = threadIdx.x;
  const int lane = tid & 63;
  const int w = tid >> 6;          // 0..7
  const int l31 = lane & 31;
  const int hi = lane >> 5;

  // head-contiguous XCD swizzle: 256 blocks, 32/XCD -> 4 full heads per XCD L2
  const int bid = blockIdx.x;
  const int nat = (bid & 7) * 32 + (bid >> 3);
  const int qt = nat & 7;
  const int bh = nat >> 3;
  const int b = bh >> 4, h = bh & 15;

  const size_t hk = (size_t)bh * N_ * D_;
  const size_t hv = (size_t)bh * D_ * N_;
  const int qrow = qt * 256 + w * 32 + l31;  // this lane's q (B-frag col)

  // Q fragments: B-operand, col=q=l31, k = d = kt*16 + hi*8 + j
  bf16x8 qf[4];
#pragma unroll
  for (int kt = 0; kt < 4; ++kt)
    qf[kt] = *reinterpret_cast<const bf16x8*>(
        &q[hk + (size_t)qrow * D_ + kt * 16 + hi * 8]);

  // staging: 512 threads x (1 K-chunk + 1 V-chunk) of 16B, reg-staged
  const int prow = tid >> 3;                 // 0..63
  const int pchk = tid & 7;
  const int swz = (pchk ^ (prow & 7)) * 8;

  u16x8 kr, vr;
  auto issueK = [&](int t) {
    kr = *reinterpret_cast<const u16x8*>(&k[hk + (size_t)(t * 64 + prow) * D_ + pchk * 8]);
  };
  auto issueV = [&](int t) {
    vr = *reinterpret_cast<const u16x8*>(&vt[hv + (size_t)prow * N_ + t * 64 + pchk * 8]);
  };
  auto commitK = [&](int buf) { *reinterpret_cast<u16x8*>(&Kl[buf][prow][swz]) = kr; };
  auto commitV = [&](int buf) { *reinterpret_cast<u16x8*>(&Vl[buf][prow][swz]) = vr; };

  f32x16 accO[2] = {};
  float lrun = 0.f;   // per-half-wave partial; combined once in epilogue
  const int b7 = l31 & 7;
  const int NT = N_ / 64;

  f32x16 sA[2], sB[2];

  // QK(t) into SC from Kl[t&1] — kt OUTER / kb INNER: the two accumulate
  // chains (SC[0], SC[1]) alternate on the matrix pipe.
#define QK_MFMA(T, SC)                                                        \
  do {                                                                        \
    f32x16 z_ = {};                                                           \
    SC[0] = z_; SC[1] = z_;                                                   \
    _Pragma("unroll")                                                         \
    for (int kt = 0; kt < 4; ++kt)                                            \
      _Pragma("unroll")                                                       \
      for (int kb = 0; kb < 2; ++kb) {                                        \
        bf16x8 kf = *reinterpret_cast<const bf16x8*>(                         \
            &Kl[(T) & 1][kb * 32 + l31][(((kt * 2 + hi) ^ b7)) * 8]);         \
        SC[kb] = __builtin_amdgcn_mfma_f32_32x32x16_bf16(kf, qf[kt], SC[kb], 0, 0, 0); \
      }                                                                       \
  } while (0)

  // softmax(SP) + PV with Vl[VB] — kvc OUTER / db INNER interleaves accO[0/1]
#define SMPV(SP, VB)                                                          \
  do {                                                                        \
    _Pragma("unroll")                                                         \
    for (int kb = 0; kb < 2; ++kb)                                            \
      _Pragma("unroll")                                                       \
      for (int i = 0; i < 16; ++i) SP[kb][i] = __builtin_exp2f(SP[kb][i]);    \
    float sloc[16];                                                           \
    _Pragma("unroll")                                                         \
    for (int i = 0; i < 16; ++i) sloc[i] = SP[0][i] + SP[1][i];               \
    _Pragma("unroll")                                                         \
    for (int st = 8; st > 0; st >>= 1)                                        \
      _Pragma("unroll")                                                       \
      for (int i = 0; i < 8; ++i)                                             \
        if (i < st) sloc[i] += sloc[i + st];                                  \
    lrun += sloc[0];                                                          \
    bf16x8 PA[4];                                                             \
    _Pragma("unroll")                                                         \
    for (int kvc = 0; kvc < 4; ++kvc) {                                       \
      const int kb = kvc >> 1, base = (kvc & 1) * 8;                          \
      union { unsigned u[4]; bf16x8 v; } pa;                                  \
      _Pragma("unroll")                                                       \
      for (int wd = 0; wd < 4; ++wd)                                          \
        pa.u[wd] = cvt_pk_bf16(SP[kb][base + 2 * wd], SP[kb][base + 2 * wd + 1]); \
      PA[kvc] = pa.v;                                                         \
    }                                                                         \
    _Pragma("unroll")                                                         \
    for (int kvc = 0; kvc < 4; ++kvc)                                         \
      _Pragma("unroll")                                                       \
      for (int db = 0; db < 2; ++db) {                                        \
        bf16x8 vf = *reinterpret_cast<const bf16x8*>(                         \
            &Vl[VB][db * 32 + l31][(((kvc * 2 + hi) ^ b7)) * 8]);             \
        accO[db] = __builtin_amdgcn_mfma_f32_32x32x16_bf16(vf, PA[kvc], accO[db], 0, 0, 0); \
      }                                                                       \
  } while (0)

  // iter t: QK(t) || softmax+PV(t-1); stage K(t+1) into (t+1)&1, V(t) into t&1.
#define BODY(T, SP, SC)                                                       \
  do {                                                                        \
    const int t_ = (T);                                                       \
    if (t_ + 1 < NT) issueK(t_ + 1);                                          \
    issueV(t_);                                                               \
    QK_MFMA(t_, SC);                                                          \
    SMPV(SP, (t_ - 1) & 1);                                                   \
    if (t_ + 1 < NT) commitK((t_ + 1) & 1);                                   \
    commitV(t_ & 1);                                                          \
    __syncthreads();                                                          \
  } while (0)

  // prologue: stage K(0)
  issueK(0);
  commitK(0);
  __syncthreads();

  // iter 0 (peeled: no previous tile)
  issueK(1);
  issueV(0);
  QK_MFMA(0, sA);
  commitK(1);
  commitV(0);
  __syncthreads();

  for (int tt = 1; tt + 1 < NT; tt += 2) {
    BODY(tt, sA, sB);
    BODY(tt + 1, sB, sA);
  }
  BODY(NT - 1, sA, sB);  // NT even: last iter, prev state in sA

  // tail: finish tile NT-1 (state in sB), V buffer (NT-1)&1
  SMPV(sB, (NT - 1) & 1);

  // epilogue: combine the two half-wave lrun partials once, then normalize
  {
    unsigned ua = __float_as_uint(lrun), ub = ua;
    auto rr = __builtin_amdgcn_permlane32_swap(ua, ub, false, false);
    lrun = __uint_as_float(rr[0]) + __uint_as_float(rr[1]);
  }
  float rl = 1.0f / lrun;
  const size_t obase = ((size_t)b * N_ + qrow) * C_ + h * 64;
#pragma unroll
  for (int db = 0; db < 2; ++db)
#pragma unroll
    for (int rg = 0; rg < 4; ++rg) {
      ushort4 pk;
      pk.x = f2bf(accO[db][rg * 4 + 0] * rl);
      pk.y = f2bf(accO[db][rg * 4 + 1] * rl);
      pk.z = f2bf(accO[db][rg * 4 + 2] * rl);
      pk.w = f2bf(accO[db][rg * 4 + 3] * rl);
      *reinterpret_cast<ushort4*>(&o[obase + db * 32 + rg * 8 + hi * 4]) = pk;
    }
#undef BODY
#undef SMPV
#undef QK_MFMA
}

extern "C" void kernel_launch(void* const* d_in, const int* in_sizes, int n_in,
                              void* d_out, int out_size, void* d_ws, size_t ws_size,
                              hipStream_t stream) {
  const float* x      = (const float*)d_in[0];
  const float* qkv_w  = (const float*)d_in[1];
  const float* proj_w = (const float*)d_in[2];
  const float* proj_b = (const float*)d_in[3];
  const float* cosT   = (const float*)d_in[4];
  const float* sinT   = (const float*)d_in[5];
  float* out = (float*)d_out;

  unsigned short* xb     = (unsigned short*)d_ws;                 // 4096*1024
  unsigned short* wqkvb  = xb + (size_t)4096 * 1024;              // 3072*1024
  unsigned short* wprojb = wqkvb + (size_t)3072 * 1024;           // 1024*1024
  unsigned short* qb     = wprojb + (size_t)1024 * 1024;          // 32*2048*64
  unsigned short* kb     = qb + (size_t)32 * 2048 * 64;
  unsigned short* vtb    = kb + (size_t)32 * 2048 * 64;           // [bh][d][n']
  unsigned short* ab     = vtb + (size_t)32 * 2048 * 64;          // 4096*1024
  float2* csT            = (float2*)(ab + (size_t)4096 * 1024);   // 2048*32 float2

  cast3_f32_bf16<<<8448, 256, 0, stream>>>(x, qkv_w, proj_w, xb, wqkvb, wprojb,
                                           cosT, sinT, csT);

  gemm_bt<1><<<768, 256, 0, stream>>>(xb, wqkvb, 4096, 3072, 1024,
                                      nullptr, nullptr, qb, kb, vtb, csT);

  attn_kernel<<<256, 512, 0, stream>>>(qb, kb, vtb, ab);

  gemm_bt<0><<<256, 256, 0, stream>>>(ab, wprojb, 4096, 1024, 1024,
                                      out, proj_b, nullptr, nullptr, nullptr,
                                      csT);
}